// Round 14
// baseline (107.087 us; speedup 1.0000x reference)
//
#include <hip/hip_runtime.h>
#include <cstdint>
#include <cmath>

// Problem constants
#define B_ 8
#define C_ 512
#define N_ 1024
#define H_ 8
#define D_ 64

// I/O dtype: FLOAT32 (verified r3). Internal: bf16 MFMA workspace.
// r4: T2 swizzle. r5: bf16 weights+setprio. r6: KVBLK=64/Q-regs/XCD/exp2.
// r7-r13: nine attn variants all 33+-3us; k_out swap neutral.
// r14: ZERO-BARRIER attn (guide mistake #7 / m169: K/V is L2-resident at
//   N=1024 after XCD swizzle -> LDS staging + its barriers were overhead).
//   K/V fragments read directly from global (L2); lP wave-private only LDS
//   (16KB); NO __syncthreads in the loop. vxt deleted (residual from vv,
//   coalesced) -> proj loses its stride-512 scalar stores.

using u16 = unsigned short;

typedef __bf16 bf16x8 __attribute__((ext_vector_type(8)));
typedef float  f32x4  __attribute__((ext_vector_type(4)));
typedef unsigned short us8 __attribute__((ext_vector_type(8)));

#if __has_builtin(__builtin_amdgcn_exp2f)
#define EXP2(x) __builtin_amdgcn_exp2f(x)
#else
#define EXP2(x) exp2f(x)
#endif

#define QSCALE 0.1803368801111244f   // 0.125 * log2(e)

// ---- helpers -------------------------------------------------------------

__device__ __forceinline__ float b2f(u16 u) {
    return __uint_as_float(((uint32_t)u) << 16);
}
__device__ __forceinline__ u16 f2b(float f) {   // round-to-nearest-even
    uint32_t x = __float_as_uint(f);
    return (u16)((x + 0x7fffu + ((x >> 16) & 1u)) >> 16);
}
__device__ __forceinline__ u16 f2bt(float f) {  // truncating (P path only)
    return (u16)(__float_as_uint(f) >> 16);
}
__device__ __forceinline__ float sf(float f) {  // sanitize: non-finite/huge -> 0
    return (fabsf(f) < 1e30f) ? f : 0.0f;
}
__device__ __forceinline__ u16 sf2b(float f) { return f2b(sf(f)); }

// weight tile load: bf16-preconverted (WB) or f32-with-inline-convert
template<bool WB>
__device__ __forceinline__ us8 ldw(const void* W, size_t idx) {
    if constexpr (WB) {
        return *(const us8*)((const u16*)W + idx);
    } else {
        const float* p = (const float*)W + idx;
        float4 a = *(const float4*)p, b = *(const float4*)(p + 4);
        us8 pk;
        pk[0] = sf2b(a.x); pk[1] = sf2b(a.y); pk[2] = sf2b(a.z); pk[3] = sf2b(a.w);
        pk[4] = sf2b(b.x); pk[5] = sf2b(b.y); pk[6] = sf2b(b.z); pk[7] = sf2b(b.w);
        return pk;
    }
}

// ---- kernel 1: x f32 [B][C][N] -> x_t bf16 [B][N][C]; z==8: weight conv --

__global__ __launch_bounds__(256) void k_pre(const float* __restrict__ x,
                                             u16* __restrict__ xt,
                                             const float* __restrict__ wq,
                                             const float* __restrict__ wk,
                                             const float* __restrict__ wv,
                                             const float* __restrict__ wo,
                                             u16* __restrict__ wb) {
    const int tid = threadIdx.x;
    const int nb = blockIdx.x, cb = blockIdx.y, b = blockIdx.z;
    if (b == 8) {               // weight-convert slice (128 blocks)
        if (wb == nullptr) return;
        int base = (cb * 16 + nb) * 256 + tid;  // 0..32767
#pragma unroll
        for (int i = 0; i < 8; ++i) {
            int idx = base + i * 32768;         // 0..262143 (x4 elems)
            int m = idx >> 16;
            int off = (idx & 65535) << 2;
            const float* src = (m == 0) ? wq : (m == 1) ? wk : (m == 2) ? wv : wo;
            float4 v = *(const float4*)&src[off];
            ushort4 w;
            w.x = sf2b(v.x); w.y = sf2b(v.y); w.z = sf2b(v.z); w.w = sf2b(v.w);
            *(ushort4*)&wb[(m << 18) + off] = w;
        }
        return;
    }
    __shared__ __align__(16) u16 t[64][72];     // pad 72: 144B row stride
#pragma unroll
    for (int i = 0; i < 4; ++i) {
        int q = tid + i * 256;
        int row = q >> 4, cg = q & 15;          // row = c-local, cg*4 = n-local
        float4 v = *(const float4*)&x[((size_t)(b * C_ + cb * 64 + row) << 10) + nb * 64 + cg * 4];
        ushort4 w;
        w.x = sf2b(v.x); w.y = sf2b(v.y); w.z = sf2b(v.z); w.w = sf2b(v.w);
        *(ushort4*)&t[row][cg * 4] = w;
    }
    __syncthreads();
#pragma unroll
    for (int i = 0; i < 4; ++i) {
        int q = tid + i * 256;
        int nrow = q >> 4, cg = q & 15;         // nrow = n-local, cg*4 = c-local
        ushort4 w;
        w.x = t[cg * 4 + 0][nrow];
        w.y = t[cg * 4 + 1][nrow];
        w.z = t[cg * 4 + 2][nrow];
        w.w = t[cg * 4 + 3][nrow];
        *(ushort4*)&xt[((size_t)(b * N_ + nb * 64 + nrow) << 9) + cb * 64 + cg * 4] = w;
    }
}

// ---- kernel 2: fused QKV projection --------------------------------------
// D[n][o] = sum_c x_t[n][c] * W[o][c]
// op 0 -> qt (scaled by QSCALE), op 1 -> kt, op 2 -> v [b][o][n] ONLY.

template<bool WB>
__global__ __launch_bounds__(256) void k_proj_t(
    const u16* __restrict__ xt,
    const void* __restrict__ wq, const float* __restrict__ bq,
    const void* __restrict__ wk, const float* __restrict__ bk,
    const void* __restrict__ wv, const float* __restrict__ bv,
    u16* __restrict__ qt, u16* __restrict__ kt,
    u16* __restrict__ v) {
    __shared__ __align__(16) u16 lA[128 * 64];
    __shared__ __align__(16) u16 lB[128 * 64];
    const int tid = threadIdx.x;
    const int op = blockIdx.z >> 3, b = blockIdx.z & 7;
    const int n0 = blockIdx.x * 128, o0 = blockIdx.y * 128;
    const void*  W  = (op == 0) ? wq : (op == 1) ? wk : wv;
    const float* BI = (op == 0) ? bq : (op == 1) ? bk : bv;
    const u16* A = xt + ((size_t)b << 19);      // b*N*C
    const int lane = tid & 63, wave = tid >> 6;
    const int wm = (wave >> 1) * 64, wn = (wave & 1) * 64;   // wave tile: 64 n x 64 o
    const int l15 = lane & 15, lg = lane >> 4;
    const int xs = (l15 & 7) << 3;              // read-side swizzle (row&7 == l15&7)

    f32x4 acc[4][4];
    const f32x4 vzero = {0.f, 0.f, 0.f, 0.f};
#pragma unroll
    for (int i = 0; i < 4; ++i)
#pragma unroll
        for (int j = 0; j < 4; ++j) acc[i][j] = vzero;

    us8 ra[4], rwB[4];
    auto loadk = [&](int k0) {
#pragma unroll
        for (int p = 0; p < 4; ++p) {
            int slot = p * 256 + tid;           // 0..1023
            int row = slot >> 3, seg = slot & 7;
            ra[p] = *(const us8*)&A[(size_t)(n0 + row) * C_ + k0 + seg * 8];
            rwB[p] = ldw<WB>(W, (size_t)(o0 + row) * C_ + k0 + seg * 8);
        }
    };
    loadk(0);

    for (int k0 = 0; k0 < C_; k0 += 64) {
        __syncthreads();        // prev iteration's LDS readers done
#pragma unroll
        for (int p = 0; p < 4; ++p) {
            int slot = p * 256 + tid;
            int row = slot >> 3, seg = slot & 7;
            int off = row * 64 + ((seg ^ (row & 7)) << 3);   // T2 swizzle
            *(us8*)&lA[off] = ra[p];
            *(us8*)&lB[off] = rwB[p];
        }
        if (k0 + 64 < C_) loadk(k0 + 64);       // prefetch next tile during compute
        __syncthreads();        // stores visible
#pragma unroll
        for (int kk = 0; kk < 64; kk += 32) {
            const int col = (kk + lg * 8) ^ xs;
            bf16x8 af[4], bfr[4];
#pragma unroll
            for (int i = 0; i < 4; ++i)
                af[i] = *(const bf16x8*)&lA[(wm + i * 16 + l15) * 64 + col];
#pragma unroll
            for (int j = 0; j < 4; ++j)
                bfr[j] = *(const bf16x8*)&lB[(wn + j * 16 + l15) * 64 + col];
#pragma unroll
            for (int i = 0; i < 4; ++i)
#pragma unroll
                for (int j = 0; j < 4; ++j)
                    acc[i][j] = __builtin_amdgcn_mfma_f32_16x16x32_bf16(af[i], bfr[j], acc[i][j], 0, 0, 0);
        }
    }

    // epilogue: D row n = n0+wm+i*16+lg*4+r ; col o = o0+wn+j*16+l15
    if (op < 2) {
        u16* outp = (op == 0) ? qt : kt;
        const float scl = (op == 0) ? QSCALE : 1.0f;
#pragma unroll
        for (int i = 0; i < 4; ++i) {
            int nb2 = n0 + wm + i * 16 + lg * 4;
#pragma unroll
            for (int j = 0; j < 4; ++j) {
                int o = o0 + wn + j * 16 + l15;
                float bias = sf(BI[o]);
                int h = o >> 6, dl = o & 63;
                size_t base = ((size_t)b * H_ + h) << 10;   // (b*8+h)*1024
#pragma unroll
                for (int r = 0; r < 4; ++r)
                    outp[(base + nb2 + r) * D_ + dl] = f2b((acc[i][j][r] + bias) * scl);
            }
        }
    } else {
#pragma unroll
        for (int i = 0; i < 4; ++i) {
            int nb2 = n0 + wm + i * 16 + lg * 4;
#pragma unroll
            for (int j = 0; j < 4; ++j) {
                int o = o0 + wn + j * 16 + l15;
                float bias = sf(BI[o]);
                ushort4 pk;
                pk.x = f2b(acc[i][j][0] + bias);
                pk.y = f2b(acc[i][j][1] + bias);
                pk.z = f2b(acc[i][j][2] + bias);
                pk.w = f2b(acc[i][j][3] + bias);
                *(ushort4*)&v[((size_t)(b * C_ + o) << 10) + nb2] = pk;     // v[b][o][n]
            }
        }
    }
}

// ---- kernel 3: ZERO-BARRIER attention ------------------------------------
// grid 512: bid = qb*64 + bh (XCD-local K/V -> L2-resident, 256KB/head).
// 4 waves x 32 q-rows. NO LDS staging of K/V (guide m169: L2-fit data ->
// staging is overhead): fragments read directly from kt / vv. Only LDS is
// wave-private lP (16KB). NO __syncthreads in the loop -> full cross-iter
// ILP; waves fully independent.

__global__ __launch_bounds__(256) void k_attn(
    const u16* __restrict__ qt, const u16* __restrict__ kt,
    const u16* __restrict__ v, u16* __restrict__ rt) {
    __shared__ __align__(16) u16 lP[4][32 * 64];
    const int tid = threadIdx.x, lane = tid & 63, wave = tid >> 6;
    const int l15 = lane & 15, lg = lane >> 4;
    const int xs = (l15 & 7) << 3;              // lP swizzle constant
    const int bid = blockIdx.x;
    const int qb = bid >> 6, bh = bid & 63;     // same-head blocks -> same XCD
    const int b = bh >> 3, h = bh & 7;
    const size_t bh_off = (size_t)bh << 16;     // bh * N * D
    const int q0 = qb * 128;
    const int nA = wave * 32;                   // this wave's q-rows

    // Q fragments in registers
    bf16x8 qf[2][2];
#pragma unroll
    for (int nt = 0; nt < 2; ++nt)
#pragma unroll
        for (int k = 0; k < 2; ++k)
            qf[nt][k] = *(const bf16x8*)&qt[bh_off +
                (size_t)(q0 + nA + nt * 16 + l15) * D_ + k * 32 + lg * 8];

    // direct-global fragment bases
    const u16* Kb = kt + bh_off;                            // [n][d]
    const u16* Vb = v + ((size_t)(b * C_ + h * 64) << 10);  // [c][n]

    float L[2] = {0.f, 0.f};
    f32x4 oacc[2][4];
    const f32x4 vzero = {0.f, 0.f, 0.f, 0.f};
#pragma unroll
    for (int nt = 0; nt < 2; ++nt)
#pragma unroll
        for (int ct = 0; ct < 4; ++ct) oacc[nt][ct] = vzero;

    for (int mb = 0; mb < 16; ++mb) {
        // S^T: A = K rows m (direct L2 reads), B = Q regs
        f32x4 s[4][2];
#pragma unroll
        for (int mt = 0; mt < 4; ++mt)
#pragma unroll
            for (int nt = 0; nt < 2; ++nt) s[mt][nt] = vzero;
#pragma unroll
        for (int k = 0; k < 2; ++k) {
            bf16x8 aK[4];
#pragma unroll
            for (int mt = 0; mt < 4; ++mt)
                aK[mt] = *(const bf16x8*)&Kb[(size_t)(mb * 64 + mt * 16 + l15) * D_ + k * 32 + lg * 8];
            __builtin_amdgcn_s_setprio(1);
#pragma unroll
            for (int mt = 0; mt < 4; ++mt)
#pragma unroll
                for (int nt = 0; nt < 2; ++nt)
                    s[mt][nt] = __builtin_amdgcn_mfma_f32_16x16x32_bf16(aK[mt], qf[nt][k], s[mt][nt], 0, 0, 0);
            __builtin_amdgcn_s_setprio(0);
        }

        // P = exp2(S'') unnormalized; truncating bf16 pack; wave-private lP
#pragma unroll
        for (int mt = 0; mt < 4; ++mt)
#pragma unroll
            for (int nt = 0; nt < 2; ++nt) {
                float p0 = EXP2(s[mt][nt][0]);
                float p1 = EXP2(s[mt][nt][1]);
                float p2 = EXP2(s[mt][nt][2]);
                float p3 = EXP2(s[mt][nt][3]);
                L[nt] += p0 + p1 + p2 + p3;
                ushort4 pk; pk.x = f2bt(p0); pk.y = f2bt(p1); pk.z = f2bt(p2); pk.w = f2bt(p3);
                *(ushort4*)&lP[wave][(nt * 16 + l15) * 64 + ((mt * 16 + lg * 4) ^ xs)] = pk;
            }
        // no barrier: lP[wave] is wave-private

        // O += P.V : B = V rows c (direct L2 reads, n contiguous)
#pragma unroll
        for (int kk2 = 0; kk2 < 64; kk2 += 32) {
            const int colv = (kk2 + lg * 8) ^ xs;
            bf16x8 aP[2], bV[4];
#pragma unroll
            for (int nt = 0; nt < 2; ++nt)
                aP[nt] = *(const bf16x8*)&lP[wave][(nt * 16 + l15) * 64 + colv];
#pragma unroll
            for (int ct = 0; ct < 4; ++ct)
                bV[ct] = *(const bf16x8*)&Vb[((size_t)(ct * 16 + l15) << 10) + mb * 64 + kk2 + lg * 8];
            __builtin_amdgcn_s_setprio(1);
#pragma unroll
            for (int nt = 0; nt < 2; ++nt)
#pragma unroll
                for (int ct = 0; ct < 4; ++ct)
                    oacc[nt][ct] = __builtin_amdgcn_mfma_f32_16x16x32_bf16(aP[nt], bV[ct], oacc[nt][ct], 0, 0, 0);
            __builtin_amdgcn_s_setprio(0);
        }
    }

    // row-sum reduce across lane groups (same n at l, l^16, l^32, l^48)
#pragma unroll
    for (int nt = 0; nt < 2; ++nt) {
        float s2 = L[nt];
        s2 += __shfl_xor(s2, 16);
        s2 += __shfl_xor(s2, 32);
        L[nt] = s2;
    }

    // epilogue: O/L + v residual (read from vv, coalesced) -> rt [b][n][C]
#pragma unroll
    for (int nt = 0; nt < 2; ++nt) {
        float inv[4];
#pragma unroll
        for (int r = 0; r < 4; ++r) inv[r] = 1.0f / __shfl(L[nt], lg * 4 + r);
#pragma unroll
        for (int ct = 0; ct < 4; ++ct) {
            int ch = h * 64 + ct * 16 + l15;
            int nbase = q0 + nA + nt * 16 + lg * 4;
            ushort4 rv = *(const ushort4*)&v[((size_t)(b * C_ + ch) << 10) + nbase];
            const u16 rvv[4] = {rv.x, rv.y, rv.z, rv.w};
#pragma unroll
            for (int r = 0; r < 4; ++r) {
                size_t idx = ((size_t)(b * N_ + nbase + r) << 9) + ch;
                rt[idx] = f2b(oacc[nt][ct][r] * inv[r] + b2f(rvv[r]));
            }
        }
    }
}

// ---- kernel 4: final conv1x1 (r13 operand order) -------------------------
// D[n][o] = sum_c rt[n][c] * wo[o][c]; float4 stores over consecutive n.

template<bool WB>
__global__ __launch_bounds__(256) void k_out_t(
    const u16* __restrict__ rt, const void* __restrict__ wo,
    const float* __restrict__ bo, float* __restrict__ out) {
    __shared__ __align__(16) u16 lA[128 * 64];  // rt rows (n)
    __shared__ __align__(16) u16 lB[128 * 64];  // wo rows (o)
    const int tid = threadIdx.x;
    const int b = blockIdx.z;
    const int n0 = blockIdx.x * 128, o0 = blockIdx.y * 128;
    const u16* Rb = rt + ((size_t)b << 19);
    const int lane = tid & 63, wave = tid >> 6;
    const int wm = (wave >> 1) * 64, wn = (wave & 1) * 64;   // wm: n, wn: o
    const int l15 = lane & 15, lg = lane >> 4;
    const int xs = (l15 & 7) << 3;

    f32x4 acc[4][4];
    const f32x4 vzero = {0.f, 0.f, 0.f, 0.f};
#pragma unroll
    for (int i = 0; i < 4; ++i)
#pragma unroll
        for (int j = 0; j < 4; ++j) acc[i][j] = vzero;

    us8 ra[4], rwB[4];
    auto loadk = [&](int k0) {
#pragma unroll
        for (int p = 0; p < 4; ++p) {
            int slot = p * 256 + tid;
            int row = slot >> 3, seg = slot & 7;
            ra[p] = *(const us8*)&Rb[(size_t)(n0 + row) * C_ + k0 + seg * 8];
            rwB[p] = ldw<WB>(wo, (size_t)(o0 + row) * C_ + k0 + seg * 8);
        }
    };
    loadk(0);

    for (int k0 = 0; k0 < C_; k0 += 64) {
        __syncthreads();
#pragma unroll
        for (int p = 0; p < 4; ++p) {
            int slot = p * 256 + tid;
            int row = slot >> 3, seg = slot & 7;
            int off = row * 64 + ((seg ^ (row & 7)) << 3);
            *(us8*)&lA[off] = ra[p];
            *(us8*)&lB[off] = rwB[p];
        }
        if (k0 + 64 < C_) loadk(k0 + 64);
        __syncthreads();
#pragma unroll
        for (int kk = 0; kk < 64; kk += 32) {
            const int col = (kk + lg * 8) ^ xs;
            bf16x8 af[4], bfr[4];
#pragma unroll
            for (int i = 0; i < 4; ++i)
                af[i] = *(const bf16x8*)&lA[(wm + i * 16 + l15) * 64 + col];
#pragma unroll
            for (int j = 0; j < 4; ++j)
                bfr[j] = *(const bf16x8*)&lB[(wn + j * 16 + l15) * 64 + col];
#pragma unroll
            for (int i = 0; i < 4; ++i)
#pragma unroll
                for (int j = 0; j < 4; ++j)
                    acc[i][j] = __builtin_amdgcn_mfma_f32_16x16x32_bf16(af[i], bfr[j], acc[i][j], 0, 0, 0);
        }
    }

    // D row n = n0+wm+i*16+lg*4+r ; col o = o0+wn+j*16+l15 -> float4 stores
#pragma unroll
    for (int i = 0; i < 4; ++i) {
        int nb2 = n0 + wm + i * 16 + lg * 4;
#pragma unroll
        for (int j = 0; j < 4; ++j) {
            int o = o0 + wn + j * 16 + l15;
            float bias = sf(bo[o]);
            float4 st;
            st.x = acc[i][j][0] + bias;
            st.y = acc[i][j][1] + bias;
            st.z = acc[i][j][2] + bias;
            st.w = acc[i][j][3] + bias;
            *(float4*)&out[((size_t)(b * C_ + o) << 10) + nb2] = st;
        }
    }
}

// ---- launch --------------------------------------------------------------

extern "C" void kernel_launch(void* const* d_in, const int* in_sizes, int n_in,
                              void* d_out, int out_size, void* d_ws, size_t ws_size,
                              hipStream_t stream) {
    const float* x  = (const float*)d_in[0];
    const float* wq = (const float*)d_in[1];
    const float* bq = (const float*)d_in[2];
    const float* wk = (const float*)d_in[3];
    const float* bk = (const float*)d_in[4];
    const float* wv = (const float*)d_in[5];
    const float* bv = (const float*)d_in[6];
    const float* wo = (const float*)d_in[7];
    const float* bo = (const float*)d_in[8];
    float* out = (float*)d_out;
    u16* ws = (u16*)d_ws;

    const size_t T = (size_t)B_ * C_ * N_;      // 4,194,304 elements per tensor
    const size_t WSZ = (size_t)4 * C_ * C_;     // 1,048,576 elems (bf16 weights)
    if (ws_size < 5 * T * sizeof(u16)) return;  // guard -> out stays 0

    u16* xt  = ws;            // [B][N][C] bf16 (reused as rt after proj)
    u16* qt  = ws + 1 * T;    // [B][H][N][D] (pre-scaled by 0.125*log2e)
    u16* kt  = ws + 2 * T;    // [B][H][N][D]
    u16* vv  = ws + 3 * T;    // [B][C][N]
    u16* rt  = xt;            // alias: x_t dead after k_proj
    u16* wb  = ws + 5 * T;    // bf16 weights [wq|wk|wv|wo], if they fit
                              // (slot 4*T..5*T now unused; kept for layout)

    const bool wbfit = ws_size >= (5 * T + WSZ) * sizeof(u16);

    k_pre<<<dim3(16, 8, 9), 256, 0, stream>>>(x, xt, wq, wk, wv, wo,
                                              wbfit ? wb : (u16*)nullptr);
    if (wbfit) {
        k_proj_t<true><<<dim3(8, 4, 24), 256, 0, stream>>>(
            xt, wb, bq, wb + 262144, bk, wb + 524288, bv, qt, kt, vv);
    } else {
        k_proj_t<false><<<dim3(8, 4, 24), 256, 0, stream>>>(
            xt, wq, bq, wk, bk, wv, bv, qt, kt, vv);
    }
    k_attn<<<dim3(512), 256, 0, stream>>>(qt, kt, vv, rt);
    if (wbfit) {
        k_out_t<true><<<dim3(8, 4, 8), 256, 0, stream>>>(rt, wb + 786432, bo, out);
    } else {
        k_out_t<false><<<dim3(8, 4, 8), 256, 0, stream>>>(rt, wo, bo, out);
    }
}

// Round 15
// 75.625 us; speedup vs baseline: 1.4160x; 1.4160x over previous
//
#include <hip/hip_runtime.h>
#include <cstdint>
#include <cmath>

// Problem constants
#define B_ 8
#define C_ 512
#define N_ 1024
#define H_ 8
#define D_ 64

// I/O dtype: FLOAT32 (verified r3). Internal: bf16 MFMA workspace.
// r4: T2 swizzle (conflicts 3.07e7->2.6e6). r5: bf16 weights+setprio.
// r6: KVBLK=64, Q-in-regs, XCD grid, exp2 fold.
// r7-r14: ten attn variants bracket 33+-3us (occupancy r8 & operand-feed
//   latency r14 confirmed by failing in predicted directions); LDS staging
//   justified; best build = r9 split-KV @ 75.86us.
// r15: CONSOLIDATION — exact r9 restore (r14 was a 107us regression).

using u16 = unsigned short;

typedef __bf16 bf16x8 __attribute__((ext_vector_type(8)));
typedef float  f32x4  __attribute__((ext_vector_type(4)));
typedef unsigned short us8 __attribute__((ext_vector_type(8)));

#if __has_builtin(__builtin_amdgcn_exp2f)
#define EXP2(x) __builtin_amdgcn_exp2f(x)
#else
#define EXP2(x) exp2f(x)
#endif

#define QSCALE 0.1803368801111244f   // 0.125 * log2(e)

// ---- helpers -------------------------------------------------------------

__device__ __forceinline__ float b2f(u16 u) {
    return __uint_as_float(((uint32_t)u) << 16);
}
__device__ __forceinline__ u16 f2b(float f) {   // round-to-nearest-even
    uint32_t x = __float_as_uint(f);
    return (u16)((x + 0x7fffu + ((x >> 16) & 1u)) >> 16);
}
__device__ __forceinline__ u16 f2bt(float f) {  // truncating (P path only)
    return (u16)(__float_as_uint(f) >> 16);
}
__device__ __forceinline__ float sf(float f) {  // sanitize: non-finite/huge -> 0
    return (fabsf(f) < 1e30f) ? f : 0.0f;
}
__device__ __forceinline__ u16 sf2b(float f) { return f2b(sf(f)); }

// weight tile load: bf16-preconverted (WB) or f32-with-inline-convert
template<bool WB>
__device__ __forceinline__ us8 ldw(const void* W, size_t idx) {
    if constexpr (WB) {
        return *(const us8*)((const u16*)W + idx);
    } else {
        const float* p = (const float*)W + idx;
        float4 a = *(const float4*)p, b = *(const float4*)(p + 4);
        us8 pk;
        pk[0] = sf2b(a.x); pk[1] = sf2b(a.y); pk[2] = sf2b(a.z); pk[3] = sf2b(a.w);
        pk[4] = sf2b(b.x); pk[5] = sf2b(b.y); pk[6] = sf2b(b.z); pk[7] = sf2b(b.w);
        return pk;
    }
}

// ---- kernel 1: x f32 [B][C][N] -> x_t bf16 [B][N][C]; z==8: weight conv --

__global__ __launch_bounds__(256) void k_pre(const float* __restrict__ x,
                                             u16* __restrict__ xt,
                                             const float* __restrict__ wq,
                                             const float* __restrict__ wk,
                                             const float* __restrict__ wv,
                                             const float* __restrict__ wo,
                                             u16* __restrict__ wb) {
    const int tid = threadIdx.x;
    const int nb = blockIdx.x, cb = blockIdx.y, b = blockIdx.z;
    if (b == 8) {               // weight-convert slice (128 blocks)
        if (wb == nullptr) return;
        int base = (cb * 16 + nb) * 256 + tid;  // 0..32767
#pragma unroll
        for (int i = 0; i < 8; ++i) {
            int idx = base + i * 32768;         // 0..262143 (x4 elems)
            int m = idx >> 16;
            int off = (idx & 65535) << 2;
            const float* src = (m == 0) ? wq : (m == 1) ? wk : (m == 2) ? wv : wo;
            float4 v = *(const float4*)&src[off];
            ushort4 w;
            w.x = sf2b(v.x); w.y = sf2b(v.y); w.z = sf2b(v.z); w.w = sf2b(v.w);
            *(ushort4*)&wb[(m << 18) + off] = w;
        }
        return;
    }
    __shared__ __align__(16) u16 t[64][72];     // pad 72: 144B row stride
#pragma unroll
    for (int i = 0; i < 4; ++i) {
        int q = tid + i * 256;
        int row = q >> 4, cg = q & 15;          // row = c-local, cg*4 = n-local
        float4 v = *(const float4*)&x[((size_t)(b * C_ + cb * 64 + row) << 10) + nb * 64 + cg * 4];
        ushort4 w;
        w.x = sf2b(v.x); w.y = sf2b(v.y); w.z = sf2b(v.z); w.w = sf2b(v.w);
        *(ushort4*)&t[row][cg * 4] = w;
    }
    __syncthreads();
#pragma unroll
    for (int i = 0; i < 4; ++i) {
        int q = tid + i * 256;
        int nrow = q >> 4, cg = q & 15;         // nrow = n-local, cg*4 = c-local
        ushort4 w;
        w.x = t[cg * 4 + 0][nrow];
        w.y = t[cg * 4 + 1][nrow];
        w.z = t[cg * 4 + 2][nrow];
        w.w = t[cg * 4 + 3][nrow];
        *(ushort4*)&xt[((size_t)(b * N_ + nb * 64 + nrow) << 9) + cb * 64 + cg * 4] = w;
    }
}

// ---- kernel 2: fused QKV projection --------------------------------------
// D[n][o] = sum_c x_t[n][c] * W[o][c]
// op 0 -> qt (scaled by QSCALE for exp2 softmax), op 1 -> kt,
// op 2 -> v [b][o][n] AND vxt [b][n][o]

template<bool WB>
__global__ __launch_bounds__(256) void k_proj_t(
    const u16* __restrict__ xt,
    const void* __restrict__ wq, const float* __restrict__ bq,
    const void* __restrict__ wk, const float* __restrict__ bk,
    const void* __restrict__ wv, const float* __restrict__ bv,
    u16* __restrict__ qt, u16* __restrict__ kt,
    u16* __restrict__ v,  u16* __restrict__ vxt) {
    __shared__ __align__(16) u16 lA[128 * 64];
    __shared__ __align__(16) u16 lB[128 * 64];
    const int tid = threadIdx.x;
    const int op = blockIdx.z >> 3, b = blockIdx.z & 7;
    const int n0 = blockIdx.x * 128, o0 = blockIdx.y * 128;
    const void*  W  = (op == 0) ? wq : (op == 1) ? wk : wv;
    const float* BI = (op == 0) ? bq : (op == 1) ? bk : bv;
    const u16* A = xt + ((size_t)b << 19);      // b*N*C
    const int lane = tid & 63, wave = tid >> 6;
    const int wm = (wave >> 1) * 64, wn = (wave & 1) * 64;   // wave tile: 64 n x 64 o
    const int l15 = lane & 15, lg = lane >> 4;
    const int xs = (l15 & 7) << 3;              // read-side swizzle (row&7 == l15&7)

    f32x4 acc[4][4];
    const f32x4 vzero = {0.f, 0.f, 0.f, 0.f};
#pragma unroll
    for (int i = 0; i < 4; ++i)
#pragma unroll
        for (int j = 0; j < 4; ++j) acc[i][j] = vzero;

    us8 ra[4], rwB[4];
    auto loadk = [&](int k0) {
#pragma unroll
        for (int p = 0; p < 4; ++p) {
            int slot = p * 256 + tid;           // 0..1023
            int row = slot >> 3, seg = slot & 7;
            ra[p] = *(const us8*)&A[(size_t)(n0 + row) * C_ + k0 + seg * 8];
            rwB[p] = ldw<WB>(W, (size_t)(o0 + row) * C_ + k0 + seg * 8);
        }
    };
    loadk(0);

    for (int k0 = 0; k0 < C_; k0 += 64) {
        __syncthreads();        // prev iteration's LDS readers done
#pragma unroll
        for (int p = 0; p < 4; ++p) {
            int slot = p * 256 + tid;
            int row = slot >> 3, seg = slot & 7;
            int off = row * 64 + ((seg ^ (row & 7)) << 3);   // T2 swizzle
            *(us8*)&lA[off] = ra[p];
            *(us8*)&lB[off] = rwB[p];
        }
        if (k0 + 64 < C_) loadk(k0 + 64);       // prefetch next tile during compute
        __syncthreads();        // stores visible
#pragma unroll
        for (int kk = 0; kk < 64; kk += 32) {
            const int col = (kk + lg * 8) ^ xs;
            bf16x8 af[4], bfr[4];
#pragma unroll
            for (int i = 0; i < 4; ++i)
                af[i] = *(const bf16x8*)&lA[(wm + i * 16 + l15) * 64 + col];
#pragma unroll
            for (int j = 0; j < 4; ++j)
                bfr[j] = *(const bf16x8*)&lB[(wn + j * 16 + l15) * 64 + col];
#pragma unroll
            for (int i = 0; i < 4; ++i)
#pragma unroll
                for (int j = 0; j < 4; ++j)
                    acc[i][j] = __builtin_amdgcn_mfma_f32_16x16x32_bf16(af[i], bfr[j], acc[i][j], 0, 0, 0);
        }
    }

    // epilogue: D row n = n0+wm+i*16+lg*4+r ; col o = o0+wn+j*16+l15
    if (op < 2) {
        u16* outp = (op == 0) ? qt : kt;
        const float scl = (op == 0) ? QSCALE : 1.0f;
#pragma unroll
        for (int i = 0; i < 4; ++i) {
            int nb2 = n0 + wm + i * 16 + lg * 4;
#pragma unroll
            for (int j = 0; j < 4; ++j) {
                int o = o0 + wn + j * 16 + l15;
                float bias = sf(BI[o]);
                int h = o >> 6, dl = o & 63;
                size_t base = ((size_t)b * H_ + h) << 10;   // (b*8+h)*1024
#pragma unroll
                for (int r = 0; r < 4; ++r)
                    outp[(base + nb2 + r) * D_ + dl] = f2b((acc[i][j][r] + bias) * scl);
            }
        }
    } else {
#pragma unroll
        for (int i = 0; i < 4; ++i) {
            int nb2 = n0 + wm + i * 16 + lg * 4;
#pragma unroll
            for (int j = 0; j < 4; ++j) {
                int o = o0 + wn + j * 16 + l15;
                float bias = sf(BI[o]);
                float p0 = acc[i][j][0] + bias, p1 = acc[i][j][1] + bias;
                float p2 = acc[i][j][2] + bias, p3 = acc[i][j][3] + bias;
                ushort4 pk; pk.x = f2b(p0); pk.y = f2b(p1); pk.z = f2b(p2); pk.w = f2b(p3);
                *(ushort4*)&v[((size_t)(b * C_ + o) << 10) + nb2] = pk;     // v[b][o][n]
                vxt[((size_t)(b * N_ + nb2 + 0) << 9) + o] = pk.x;          // vxt[b][n][o]
                vxt[((size_t)(b * N_ + nb2 + 1) << 9) + o] = pk.y;
                vxt[((size_t)(b * N_ + nb2 + 2) << 9) + o] = pk.z;
                vxt[((size_t)(b * N_ + nb2 + 3) << 9) + o] = pk.w;
            }
        }
    }
}

// ---- kernel 3: attention, split-KV (r9 exact; best measured) -------------
// Block 256 thr = 4 waves: wave = (kvh = wave>>1, qh = wave&1).
// Each wave: 64 q-rows (nA = qh*64) x KV tiles [kvh*8, kvh*8+8).
// 2048 waves total = 8 waves/CU. LDS 64KB -> 2 blocks/CU.
// After loop: kvh=1 waves pass unnormalized (O,L) via lP (dead) to kvh=0,
// which normalizes with combined L and writes. grid 512: bid = qb*64+bh.

__global__ __launch_bounds__(256, 2) void k_attn(
    const u16* __restrict__ qt, const u16* __restrict__ kt,
    const u16* __restrict__ v,  const u16* __restrict__ vxt,
    u16* __restrict__ rt) {
    __shared__ __align__(16) u16 lK[2][64 * 64];   // per kv-half, 16KB
    __shared__ __align__(16) u16 lV[2][64 * 64];   // 16KB
    __shared__ __align__(16) u16 lP[4][64 * 64];   // per wave, 32KB (reused as fO)
    __shared__ float lL[2][64];
    const int tid = threadIdx.x, lane = tid & 63, wave = tid >> 6;
    const int l15 = lane & 15, lg = lane >> 4;
    const int xs = (l15 & 7) << 3;              // read-side swizzle constant
    const int bid = blockIdx.x;
    const int qb = bid >> 6, bh = bid & 63;     // same-head blocks -> same XCD
    const int b = bh >> 3, h = bh & 7;
    const size_t bh_off = (size_t)bh << 16;     // bh * N * D
    const int q0 = qb * 128;
    const int kvh = wave >> 1;                  // kv half: tiles kvh*8..+7
    const int qh = wave & 1;
    const int nA = qh * 64;                     // this wave's 64 q-rows
    const int ht = tid & 127;                   // thread-in-half (staging)

    // Q fragments in registers: rows q0+nA+nt*16+l15, elems k*32+lg*8..+7
    bf16x8 qf[4][2];
#pragma unroll
    for (int nt = 0; nt < 4; ++nt)
#pragma unroll
        for (int k = 0; k < 2; ++k)
            qf[nt][k] = *(const bf16x8*)&qt[bh_off +
                (size_t)(q0 + nA + nt * 16 + l15) * D_ + k * 32 + lg * 8];

    // staging: threads of half kvh load their half's tiles (mb = kvh*8+it)
    us8 rk[4], rv[4];
    auto loadkv = [&](int it) {
        int mb = kvh * 8 + it;
#pragma unroll
        for (int p = 0; p < 4; ++p) {
            int slot = p * 128 + ht;            // 0..511
            int row = slot >> 3, seg = slot & 7;
            rk[p] = *(const us8*)&kt[bh_off + (size_t)(mb * 64 + row) * D_ + seg * 8];
            rv[p] = *(const us8*)&v[((size_t)(b * C_ + h * 64 + row) << 10) + mb * 64 + seg * 8];
        }
    };
    loadkv(0);

    float L[4] = {0.f, 0.f, 0.f, 0.f};
    f32x4 oacc[4][4];
    const f32x4 vzero = {0.f, 0.f, 0.f, 0.f};
#pragma unroll
    for (int nt = 0; nt < 4; ++nt)
#pragma unroll
        for (int ct = 0; ct < 4; ++ct) oacc[nt][ct] = vzero;

    for (int it = 0; it < 8; ++it) {
        __syncthreads();        // prev iter's lK/lV readers done
#pragma unroll
        for (int p = 0; p < 4; ++p) {
            int slot = p * 128 + ht;
            int row = slot >> 3, seg = slot & 7;
            int off = row * 64 + ((seg ^ (row & 7)) << 3);   // T2 swizzle
            *(us8*)&lK[kvh][off] = rk[p];
            *(us8*)&lV[kvh][off] = rv[p];
        }
        if (it < 7) loadkv(it + 1);     // prefetch next tile during compute
        __syncthreads();        // stores visible

        // S^T frags: rows m (4 tiles of 16), cols n (wave's 64, 4 tiles)
        f32x4 s[4][4];
#pragma unroll
        for (int mt = 0; mt < 4; ++mt)
#pragma unroll
            for (int nt = 0; nt < 4; ++nt) s[mt][nt] = vzero;
#pragma unroll
        for (int k = 0; k < 2; ++k) {
            const int col = (k * 32 + lg * 8) ^ xs;
            bf16x8 aK[4];
#pragma unroll
            for (int mt = 0; mt < 4; ++mt)
                aK[mt] = *(const bf16x8*)&lK[kvh][(mt * 16 + l15) * 64 + col];
            __builtin_amdgcn_s_setprio(1);
#pragma unroll
            for (int mt = 0; mt < 4; ++mt)
#pragma unroll
                for (int nt = 0; nt < 4; ++nt)
                    s[mt][nt] = __builtin_amdgcn_mfma_f32_16x16x32_bf16(aK[mt], qf[nt][k], s[mt][nt], 0, 0, 0);
            __builtin_amdgcn_s_setprio(0);
        }

        // P = exp2(S'') unnormalized; truncating bf16 pack; wave-private lP
#pragma unroll
        for (int mt = 0; mt < 4; ++mt)
#pragma unroll
            for (int nt = 0; nt < 4; ++nt) {
                float p0 = EXP2(s[mt][nt][0]);
                float p1 = EXP2(s[mt][nt][1]);
                float p2 = EXP2(s[mt][nt][2]);
                float p3 = EXP2(s[mt][nt][3]);
                L[nt] += p0 + p1 + p2 + p3;     // in-lane partial per lane-group
                ushort4 pk; pk.x = f2bt(p0); pk.y = f2bt(p1); pk.z = f2bt(p2); pk.w = f2bt(p3);
                *(ushort4*)&lP[wave][(nt * 16 + l15) * 64 + ((mt * 16 + lg * 4) ^ xs)] = pk;
            }
        // no barrier: lP[wave] is wave-private

        // O += P.V
#pragma unroll
        for (int kk2 = 0; kk2 < 64; kk2 += 32) {
            const int colv = (kk2 + lg * 8) ^ xs;
            bf16x8 aP[4], bV[4];
#pragma unroll
            for (int nt = 0; nt < 4; ++nt)
                aP[nt] = *(const bf16x8*)&lP[wave][(nt * 16 + l15) * 64 + colv];
#pragma unroll
            for (int ct = 0; ct < 4; ++ct)
                bV[ct] = *(const bf16x8*)&lV[kvh][(ct * 16 + l15) * 64 + colv];
            __builtin_amdgcn_s_setprio(1);
#pragma unroll
            for (int nt = 0; nt < 4; ++nt)
#pragma unroll
                for (int ct = 0; ct < 4; ++ct)
                    oacc[nt][ct] = __builtin_amdgcn_mfma_f32_16x16x32_bf16(aP[nt], bV[ct], oacc[nt][ct], 0, 0, 0);
            __builtin_amdgcn_s_setprio(0);
        }
    }

    // row-sum reduce across lane groups (same n at l, l^16, l^32, l^48)
#pragma unroll
    for (int nt = 0; nt < 4; ++nt) {
        float s2 = L[nt];
        s2 += __shfl_xor(s2, 16);
        s2 += __shfl_xor(s2, 32);
        L[nt] = s2;
    }

    // ---- combine kv halves: kvh=1 -> LDS (lP dead) -> kvh=0 adds ---------
    __syncthreads();            // all loop-phase LDS reads complete
    float* fO = (float*)&lP[0][0];      // [2][64][64] f32 = 32KB (all of lP)
    if (kvh == 1) {
#pragma unroll
        for (int nt = 0; nt < 4; ++nt) {
            if (lg == 0) lL[qh][nt * 16 + l15] = L[nt];
#pragma unroll
            for (int ct = 0; ct < 4; ++ct) {
#pragma unroll
                for (int r = 0; r < 4; ++r) {
                    int n = nt * 16 + lg * 4 + r;
                    int c = (ct * 16 + l15) ^ (((n >> 2) & 1) << 4);  // 2-way swz
                    fO[qh * 4096 + n * 64 + c] = oacc[nt][ct][r];
                }
            }
        }
    }
    __syncthreads();
    if (kvh == 1) return;

    // kvh=0: add partner's partials, normalize, add residual, write
#pragma unroll
    for (int nt = 0; nt < 4; ++nt) {
        L[nt] += lL[qh][nt * 16 + l15];
#pragma unroll
        for (int ct = 0; ct < 4; ++ct) {
#pragma unroll
            for (int r = 0; r < 4; ++r) {
                int n = nt * 16 + lg * 4 + r;
                int c = (ct * 16 + l15) ^ (((n >> 2) & 1) << 4);
                oacc[nt][ct][r] += fO[qh * 4096 + n * 64 + c];
            }
        }
    }

    // epilogue: O/L + vx residual -> rt [b][n][C]
#pragma unroll
    for (int nt = 0; nt < 4; ++nt) {
        float inv[4];
#pragma unroll
        for (int r = 0; r < 4; ++r) inv[r] = 1.0f / __shfl(L[nt], lg * 4 + r);
#pragma unroll
        for (int ct = 0; ct < 4; ++ct) {
            int ch = h * 64 + ct * 16 + l15;
#pragma unroll
            for (int r = 0; r < 4; ++r) {
                int n = q0 + nA + nt * 16 + lg * 4 + r;
                size_t idx = ((size_t)(b * N_ + n) << 9) + ch;
                rt[idx] = f2b(oacc[nt][ct][r] * inv[r] + b2f(vxt[idx]));
            }
        }
    }
}

// ---- kernel 4: final conv1x1 ---------------------------------------------
// D[o][n] = sum_c wo[o][c] * rt[n][c]; out f32 [b][o][n]

template<bool WB>
__global__ __launch_bounds__(256) void k_out_t(
    const u16* __restrict__ rt, const void* __restrict__ wo,
    const float* __restrict__ bo, float* __restrict__ out) {
    __shared__ __align__(16) u16 lA[128 * 64];  // wo rows (o)
    __shared__ __align__(16) u16 lB[128 * 64];  // rt rows (n)
    const int tid = threadIdx.x;
    const int b = blockIdx.z;
    const int n0 = blockIdx.x * 128, o0 = blockIdx.y * 128;
    const u16* Rb = rt + ((size_t)b << 19);
    const int lane = tid & 63, wave = tid >> 6;
    const int wm = (wave >> 1) * 64, wn = (wave & 1) * 64;   // wm: o, wn: n
    const int l15 = lane & 15, lg = lane >> 4;
    const int xs = (l15 & 7) << 3;

    f32x4 acc[4][4];
    const f32x4 vzero = {0.f, 0.f, 0.f, 0.f};
#pragma unroll
    for (int i = 0; i < 4; ++i)
#pragma unroll
        for (int j = 0; j < 4; ++j) acc[i][j] = vzero;

    us8 rb[4], rwB[4];
    auto loadk = [&](int k0) {
#pragma unroll
        for (int p = 0; p < 4; ++p) {
            int slot = p * 256 + tid;
            int row = slot >> 3, seg = slot & 7;
            rwB[p] = ldw<WB>(wo, (size_t)(o0 + row) * C_ + k0 + seg * 8);
            rb[p] = *(const us8*)&Rb[(size_t)(n0 + row) * C_ + k0 + seg * 8];
        }
    };
    loadk(0);

    for (int k0 = 0; k0 < C_; k0 += 64) {
        __syncthreads();
#pragma unroll
        for (int p = 0; p < 4; ++p) {
            int slot = p * 256 + tid;
            int row = slot >> 3, seg = slot & 7;
            int off = row * 64 + ((seg ^ (row & 7)) << 3);
            *(us8*)&lA[off] = rwB[p];
            *(us8*)&lB[off] = rb[p];
        }
        if (k0 + 64 < C_) loadk(k0 + 64);
        __syncthreads();
#pragma unroll
        for (int kk = 0; kk < 64; kk += 32) {
            const int col = (kk + lg * 8) ^ xs;
            bf16x8 af[4], bfr[4];
#pragma unroll
            for (int i = 0; i < 4; ++i)
                af[i] = *(const bf16x8*)&lA[(wm + i * 16 + l15) * 64 + col];
#pragma unroll
            for (int j = 0; j < 4; ++j)
                bfr[j] = *(const bf16x8*)&lB[(wn + j * 16 + l15) * 64 + col];
#pragma unroll
            for (int i = 0; i < 4; ++i)
#pragma unroll
                for (int j = 0; j < 4; ++j)
                    acc[i][j] = __builtin_amdgcn_mfma_f32_16x16x32_bf16(af[i], bfr[j], acc[i][j], 0, 0, 0);
        }
    }

    // D row o = o0+wm+i*16+lg*4+r ; col n = n0+wn+j*16+l15
#pragma unroll
    for (int i = 0; i < 4; ++i) {
#pragma unroll
        for (int j = 0; j < 4; ++j) {
            int nn = n0 + wn + j * 16 + l15;
#pragma unroll
            for (int r = 0; r < 4; ++r) {
                int o = o0 + wm + i * 16 + lg * 4 + r;
                out[((size_t)(b * C_ + o) << 10) + nn] = acc[i][j][r] + sf(bo[o]);
            }
        }
    }
}

// ---- launch --------------------------------------------------------------

extern "C" void kernel_launch(void* const* d_in, const int* in_sizes, int n_in,
                              void* d_out, int out_size, void* d_ws, size_t ws_size,
                              hipStream_t stream) {
    const float* x  = (const float*)d_in[0];
    const float* wq = (const float*)d_in[1];
    const float* bq = (const float*)d_in[2];
    const float* wk = (const float*)d_in[3];
    const float* bk = (const float*)d_in[4];
    const float* wv = (const float*)d_in[5];
    const float* bv = (const float*)d_in[6];
    const float* wo = (const float*)d_in[7];
    const float* bo = (const float*)d_in[8];
    float* out = (float*)d_out;
    u16* ws = (u16*)d_ws;

    const size_t T = (size_t)B_ * C_ * N_;      // 4,194,304 elements per tensor
    const size_t WSZ = (size_t)4 * C_ * C_;     // 1,048,576 elems (bf16 weights)
    if (ws_size < 5 * T * sizeof(u16)) return;  // diagnostic guard -> out stays 0

    u16* xt  = ws;            // [B][N][C] bf16 (reused as rt after proj)
    u16* qt  = ws + 1 * T;    // [B][H][N][D] (pre-scaled by 0.125*log2e)
    u16* kt  = ws + 2 * T;    // [B][H][N][D]
    u16* vv  = ws + 3 * T;    // [B][C][N]
    u16* vxt = ws + 4 * T;    // [B][N][C]
    u16* rt  = xt;            // alias: x_t dead after k_proj
    u16* wb  = ws + 5 * T;    // bf16 weights [wq|wk|wv|wo], if they fit

    const bool wbfit = ws_size >= (5 * T + WSZ) * sizeof(u16);

    k_pre<<<dim3(16, 8, 9), 256, 0, stream>>>(x, xt, wq, wk, wv, wo,
                                              wbfit ? wb : (u16*)nullptr);
    if (wbfit) {
        k_proj_t<true><<<dim3(8, 4, 24), 256, 0, stream>>>(
            xt, wb, bq, wb + 262144, bk, wb + 524288, bv, qt, kt, vv, vxt);
    } else {
        k_proj_t<false><<<dim3(8, 4, 24), 256, 0, stream>>>(
            xt, wq, bq, wk, bk, wv, bv, qt, kt, vv, vxt);
    }
    k_attn<<<dim3(512), 256, 0, stream>>>(qt, kt, vv, vxt, rt);
    if (wbfit) {
        k_out_t<true><<<dim3(8, 4, 8), 256, 0, stream>>>(rt, wb + 786432, bo, out);
    } else {
        k_out_t<false><<<dim3(8, 4, 8), 256, 0, stream>>>(rt, wo, bo, out);
    }
}